// Round 2
// baseline (1222.240 us; speedup 1.0000x reference)
//
#include <hip/hip_runtime.h>

// Problem constants
#define N_ROWS 32768   // B*T*H*W = 8*16*16*16
#define DIM    256
#define K_EMB  2048
#define OUT_ZQ_SIZE (N_ROWS * DIM)   // 8388608

// Tiling
#define BM 128
#define BK 128
#define KC 32
#define TM 8
#define TN 8
// thread grid 16 (tx) x 16 (ty), 256 threads

// ---------------- numpy-pairwise row sum of squares ----------------
// Emulates np.sum(x*x, axis=-1) for rows of 256 f32 exactly:
// pairwise_sum(256) = P(a[0:128]) + P(a[128:256]);
// P(block128): r[j]=a[j]; for i=8..120 step 8: r[j]+=a[i+j];
//              res = ((r0+r1)+(r2+r3)) + ((r4+r5)+(r6+r7))
// 16 lanes per row: lane = half*8 + j.
__global__ __launch_bounds__(256) void sq_pairwise(const float* __restrict__ src,
                                                   float* __restrict__ dst,
                                                   int nrows) {
    int gid = blockIdx.x * 256 + threadIdx.x;
    int row = gid >> 4;
    int lane = gid & 15;
    if (row >= nrows) return;
    const float* p = src + row * DIM;
    int base = (lane >> 3) * 128 + (lane & 7);
    float r = __fmul_rn(p[base], p[base]);
    #pragma unroll
    for (int i = 1; i < 16; i++) {
        float v = p[base + 8 * i];
        r = __fadd_rn(r, __fmul_rn(v, v));
    }
    // ((r0+r1)+(r2+r3)) + ((r4+r5)+(r6+r7)) per half
    r = __fadd_rn(r, __shfl_xor(r, 1, 64));
    r = __fadd_rn(r, __shfl_xor(r, 2, 64));
    r = __fadd_rn(r, __shfl_xor(r, 4, 64));
    // half0 + half1
    r = __fadd_rn(r, __shfl_xor(r, 8, 64));
    if (lane == 0) dst[row] = r;
}

// ---------------- main kernel ----------------
__global__ __launch_bounds__(256) void vq_main(const float* __restrict__ z,
                                               const float* __restrict__ emb,
                                               const float* __restrict__ e2np,
                                               const float* __restrict__ z2np,
                                               float* __restrict__ out_zq,
                                               float* __restrict__ out_idx,
                                               double* __restrict__ partial) {
    __shared__ float As[BM][KC + 4];        // z chunk   128 x 36 floats
    __shared__ float Bs[BK][KC + 4];        // emb chunk 128 x 36 floats
    __shared__ float2 Red[BM][16];          // per-row per-tx best: (score, idx)
    __shared__ int   RowIdx[BM];
    __shared__ double Wsum[4];

    const int t  = threadIdx.x;
    const int tx = t & 15;
    const int ty = t >> 4;
    const int row0 = blockIdx.x * BM;

    // per-thread rows: row0 + ty*TM + i
    float zr[TM];
    #pragma unroll
    for (int i = 0; i < TM; i++) zr[i] = z2np[row0 + ty * TM + i];

    float m1[TM];
    int   i1[TM];
    #pragma unroll
    for (int i = 0; i < TM; i++) { m1[i] = 3.4e38f; i1[i] = 0x7fffffff; }

    for (int kt = 0; kt < K_EMB; kt += BK) {
        float acc[TM][TN];
        #pragma unroll
        for (int i = 0; i < TM; i++)
            #pragma unroll
            for (int j = 0; j < TN; j++) acc[i][j] = 0.f;

        for (int dt = 0; dt < DIM; dt += KC) {
            __syncthreads();  // protect previous chunk reads before overwrite
            // stage: BM x KC floats = 1024 float4 slots, 4 per thread
            #pragma unroll
            for (int i = 0; i < 4; i++) {
                int s = i * 256 + t;       // 0..1023
                int r = s >> 3;            // 8 float4 per row
                int c = s & 7;
                float4 va = *(const float4*)(z   + (row0 + r) * DIM + dt + c * 4);
                *(float4*)&As[r][c * 4] = va;
                float4 vb = *(const float4*)(emb + (kt   + r) * DIM + dt + c * 4);
                *(float4*)&Bs[r][c * 4] = vb;
            }
            __syncthreads();

            // k-sequential chained FMA (matches BLAS sgemm microkernel rounding)
            #pragma unroll
            for (int dc = 0; dc < KC; dc += 4) {
                float4 a[TM], b[TN];
                #pragma unroll
                for (int i = 0; i < TM; i++) a[i] = *(const float4*)&As[ty * TM + i][dc];
                #pragma unroll
                for (int j = 0; j < TN; j++) b[j] = *(const float4*)&Bs[tx * TN + j][dc];
                #pragma unroll
                for (int i = 0; i < TM; i++)
                    #pragma unroll
                    for (int j = 0; j < TN; j++) {
                        float s0 = acc[i][j];
                        s0 = fmaf(a[i].x, b[j].x, s0);
                        s0 = fmaf(a[i].y, b[j].y, s0);
                        s0 = fmaf(a[i].z, b[j].z, s0);
                        s0 = fmaf(a[i].w, b[j].w, s0);
                        acc[i][j] = s0;
                    }
            }
        }

        // epilogue: emulate ref fp32: d = fl(fl(z2 + e2[k]) - 2*dot)
        // (2*acc is exact, so fma contraction of the subtract is bit-identical)
        #pragma unroll
        for (int j = 0; j < TN; j++) {
            int k = kt + tx * TN + j;
            float ek = e2np[k];
            #pragma unroll
            for (int i = 0; i < TM; i++) {
                float zpe = __fadd_rn(zr[i], ek);
                float s = zpe - 2.0f * acc[i][j];
                if (s < m1[i]) { m1[i] = s; i1[i] = k; }  // strict <: keeps lowest k
            }
        }
    }

    // publish per-thread best
    #pragma unroll
    for (int i = 0; i < TM; i++)
        Red[ty * TM + i][tx] = make_float2(m1[i], __int_as_float(i1[i]));
    __syncthreads();

    // merge across the 16 tx-threads; one thread per row; lowest-index tie-break
    if (t < BM) {
        float b1 = 3.4e38f;
        int   j1 = 0x7fffffff;
        #pragma unroll 4
        for (int x = 0; x < 16; x++) {
            float2 c = Red[t][x];
            float s = c.x; int k = __float_as_int(c.y);
            if (s < b1 || (s == b1 && k < j1)) { b1 = s; j1 = k; }
        }
        RowIdx[t] = j1;
        out_idx[row0 + t] = (float)j1;
    }
    __syncthreads();

    // gather z_q to output + loss partial: 2 threads per row, 128 floats each
    double lsum;
    {
        int row  = t >> 1;
        int d0   = (t & 1) * 128;
        int gi   = RowIdx[row];
        const float4* ev = (const float4*)(emb + gi * DIM + d0);
        const float4* zv = (const float4*)(z + (row0 + row) * DIM + d0);
        float4*       ov = (float4*)(out_zq + (row0 + row) * DIM + d0);
        float fs = 0.f;
        #pragma unroll 8
        for (int q = 0; q < 32; q++) {
            float4 e = ev[q];
            float4 zz = zv[q];
            ov[q] = e;
            float dx = e.x - zz.x, dy = e.y - zz.y, dz = e.z - zz.z, dw = e.w - zz.w;
            fs += dx * dx + dy * dy + dz * dz + dw * dw;
        }
        lsum = (double)fs;
    }
    // block reduce (deterministic)
    #pragma unroll
    for (int off = 32; off; off >>= 1) lsum += __shfl_down(lsum, off, 64);
    if ((t & 63) == 0) Wsum[t >> 6] = lsum;
    __syncthreads();
    if (t == 0) partial[blockIdx.x] = Wsum[0] + Wsum[1] + Wsum[2] + Wsum[3];
}

// ---------------- finalize: loss = 1.25 * sum / (N*D) ----------------
__global__ void finalize(const double* __restrict__ partial, float* __restrict__ out_loss) {
    double s = 0.0;
    for (int i = 0; i < 256; i++) s += partial[i];
    out_loss[0] = (float)(1.25 * s / (double)OUT_ZQ_SIZE);
}

extern "C" void kernel_launch(void* const* d_in, const int* in_sizes, int n_in,
                              void* d_out, int out_size, void* d_ws, size_t ws_size,
                              hipStream_t stream) {
    const float* z   = (const float*)d_in[0];
    const float* emb = (const float*)d_in[1];
    float* out      = (float*)d_out;
    float* out_zq   = out;                    // [N_ROWS*DIM]
    float* out_loss = out + OUT_ZQ_SIZE;      // [1]
    float* out_idx  = out + OUT_ZQ_SIZE + 1;  // [N_ROWS]

    float*  e2np    = (float*)d_ws;                          // 2048 floats
    float*  z2np    = (float*)((char*)d_ws + 8192);          // 32768 floats
    double* partial = (double*)((char*)d_ws + 8192 + 131072);// 256 doubles

    hipLaunchKernelGGL(sq_pairwise, dim3(128),  dim3(256), 0, stream, emb, e2np, K_EMB);
    hipLaunchKernelGGL(sq_pairwise, dim3(2048), dim3(256), 0, stream, z,   z2np, N_ROWS);
    hipLaunchKernelGGL(vq_main,     dim3(256),  dim3(256), 0, stream,
                       z, emb, e2np, z2np, out_zq, out_idx, partial);
    hipLaunchKernelGGL(finalize,    dim3(1),    dim3(1),   0, stream, partial, out_loss);
}

// Round 3
// 556.066 us; speedup vs baseline: 2.1980x; 2.1980x over previous
//
#include <hip/hip_runtime.h>

// Problem constants
#define N_ROWS 32768   // B*T*H*W = 8*16*16*16
#define DIM    256
#define K_EMB  2048
#define OUT_ZQ_SIZE (N_ROWS * DIM)   // 8388608

// Tiling
#define BM 128
#define BK 128
#define KC 32
#define TM 8
#define TN 8
// thread grid 16 (tx) x 16 (ty), 256 threads
// Fragment mapping (bank-conflict-free): thread rows = ty + 16*i, cols = tx + 16*j.
// Row stride between lanes = 36 floats = 4 banks -> A reads conflict-free,
// B reads 2-way (free). The old blocked mapping (ty*8+i) had stride
// 8*36 = 288 floats = 0 mod 32 banks -> 16-way conflicts = 5.1e8 cycles.

// ---------------- numpy-pairwise row sum of squares ----------------
// Emulates np.sum(x*x, axis=-1) for rows of 256 f32 exactly:
// pairwise_sum(256) = P(a[0:128]) + P(a[128:256]);
// P(block128): r[j]=a[j]; for i=8..120 step 8: r[j]+=a[i+j];
//              res = ((r0+r1)+(r2+r3)) + ((r4+r5)+(r6+r7))
__global__ __launch_bounds__(256) void sq_pairwise(const float* __restrict__ src,
                                                   float* __restrict__ dst,
                                                   int nrows) {
    int gid = blockIdx.x * 256 + threadIdx.x;
    int row = gid >> 4;
    int lane = gid & 15;
    if (row >= nrows) return;
    const float* p = src + row * DIM;
    int base = (lane >> 3) * 128 + (lane & 7);
    float r = __fmul_rn(p[base], p[base]);
    #pragma unroll
    for (int i = 1; i < 16; i++) {
        float v = p[base + 8 * i];
        r = __fadd_rn(r, __fmul_rn(v, v));
    }
    r = __fadd_rn(r, __shfl_xor(r, 1, 64));
    r = __fadd_rn(r, __shfl_xor(r, 2, 64));
    r = __fadd_rn(r, __shfl_xor(r, 4, 64));
    r = __fadd_rn(r, __shfl_xor(r, 8, 64));
    if (lane == 0) dst[row] = r;
}

// ---------------- main kernel ----------------
__global__ __launch_bounds__(256) void vq_main(const float* __restrict__ z,
                                               const float* __restrict__ emb,
                                               const float* __restrict__ e2np,
                                               const float* __restrict__ z2np,
                                               float* __restrict__ out_zq,
                                               float* __restrict__ out_idx,
                                               double* __restrict__ partial) {
    __shared__ float As[BM][KC + 4];        // z chunk   128 x 36 floats
    __shared__ float Bs[BK][KC + 4];        // emb chunk 128 x 36 floats
    __shared__ float2 Red[BM][16];          // per-row per-tx best: (score, idx)
    __shared__ int   RowIdx[BM];
    __shared__ double Wsum[4];

    const int t  = threadIdx.x;
    const int tx = t & 15;
    const int ty = t >> 4;
    const int row0 = blockIdx.x * BM;

    // per-thread rows: row0 + ty + 16*i  (interleaved)
    float zr[TM];
    #pragma unroll
    for (int i = 0; i < TM; i++) zr[i] = z2np[row0 + ty + 16 * i];

    float m1[TM];
    int   i1[TM];
    #pragma unroll
    for (int i = 0; i < TM; i++) { m1[i] = 3.4e38f; i1[i] = 0x7fffffff; }

    for (int kt = 0; kt < K_EMB; kt += BK) {
        float acc[TM][TN];
        #pragma unroll
        for (int i = 0; i < TM; i++)
            #pragma unroll
            for (int j = 0; j < TN; j++) acc[i][j] = 0.f;

        for (int dt = 0; dt < DIM; dt += KC) {
            __syncthreads();  // protect previous chunk reads before overwrite
            // stage: BM x KC floats = 1024 float4 slots, 4 per thread
            #pragma unroll
            for (int i = 0; i < 4; i++) {
                int s = i * 256 + t;       // 0..1023
                int r = s >> 3;            // 8 float4 per row
                int c = s & 7;
                float4 va = *(const float4*)(z   + (row0 + r) * DIM + dt + c * 4);
                *(float4*)&As[r][c * 4] = va;
                float4 vb = *(const float4*)(emb + (kt   + r) * DIM + dt + c * 4);
                *(float4*)&Bs[r][c * 4] = vb;
            }
            __syncthreads();

            // k-sequential chained FMA (matches BLAS-like fp32 rounding closely)
            #pragma unroll
            for (int dc = 0; dc < KC; dc += 4) {
                float4 a[TM], b[TN];
                #pragma unroll
                for (int i = 0; i < TM; i++) a[i] = *(const float4*)&As[ty + 16 * i][dc];
                #pragma unroll
                for (int j = 0; j < TN; j++) b[j] = *(const float4*)&Bs[tx + 16 * j][dc];
                #pragma unroll
                for (int i = 0; i < TM; i++)
                    #pragma unroll
                    for (int j = 0; j < TN; j++) {
                        float s0 = acc[i][j];
                        s0 = fmaf(a[i].x, b[j].x, s0);
                        s0 = fmaf(a[i].y, b[j].y, s0);
                        s0 = fmaf(a[i].z, b[j].z, s0);
                        s0 = fmaf(a[i].w, b[j].w, s0);
                        acc[i][j] = s0;
                    }
            }
        }

        // epilogue: emulate ref fp32: d = fl(fl(z2 + e2[k]) - 2*dot)
        #pragma unroll
        for (int j = 0; j < TN; j++) {
            int k = kt + tx + 16 * j;
            float ek = e2np[k];
            #pragma unroll
            for (int i = 0; i < TM; i++) {
                float zpe = __fadd_rn(zr[i], ek);
                float s = zpe - 2.0f * acc[i][j];
                if (s < m1[i]) { m1[i] = s; i1[i] = k; }  // strict <: keeps lowest k
            }
        }
    }

    // publish per-thread best
    #pragma unroll
    for (int i = 0; i < TM; i++)
        Red[ty + 16 * i][tx] = make_float2(m1[i], __int_as_float(i1[i]));
    __syncthreads();

    // merge across the 16 tx-threads; one thread per row; lowest-index tie-break
    if (t < BM) {
        float b1 = 3.4e38f;
        int   j1 = 0x7fffffff;
        #pragma unroll 4
        for (int x = 0; x < 16; x++) {
            float2 c = Red[t][x];
            float s = c.x; int k = __float_as_int(c.y);
            if (s < b1 || (s == b1 && k < j1)) { b1 = s; j1 = k; }
        }
        RowIdx[t] = j1;
        out_idx[row0 + t] = (float)j1;
    }
    __syncthreads();

    // gather z_q to output + loss partial: 2 threads per row, 128 floats each
    double lsum;
    {
        int row  = t >> 1;
        int d0   = (t & 1) * 128;
        int gi   = RowIdx[row];
        const float4* ev = (const float4*)(emb + gi * DIM + d0);
        const float4* zv = (const float4*)(z + (row0 + row) * DIM + d0);
        float4*       ov = (float4*)(out_zq + (row0 + row) * DIM + d0);
        float fs = 0.f;
        #pragma unroll 8
        for (int q = 0; q < 32; q++) {
            float4 e = ev[q];
            float4 zz = zv[q];
            ov[q] = e;
            float dx = e.x - zz.x, dy = e.y - zz.y, dz = e.z - zz.z, dw = e.w - zz.w;
            fs += dx * dx + dy * dy + dz * dz + dw * dw;
        }
        lsum = (double)fs;
    }
    // block reduce (deterministic)
    #pragma unroll
    for (int off = 32; off; off >>= 1) lsum += __shfl_down(lsum, off, 64);
    if ((t & 63) == 0) Wsum[t >> 6] = lsum;
    __syncthreads();
    if (t == 0) partial[blockIdx.x] = Wsum[0] + Wsum[1] + Wsum[2] + Wsum[3];
}

// ---------------- finalize: loss = 1.25 * sum / (N*D) ----------------
__global__ void finalize(const double* __restrict__ partial, float* __restrict__ out_loss) {
    double s = 0.0;
    for (int i = 0; i < 256; i++) s += partial[i];
    out_loss[0] = (float)(1.25 * s / (double)OUT_ZQ_SIZE);
}

extern "C" void kernel_launch(void* const* d_in, const int* in_sizes, int n_in,
                              void* d_out, int out_size, void* d_ws, size_t ws_size,
                              hipStream_t stream) {
    const float* z   = (const float*)d_in[0];
    const float* emb = (const float*)d_in[1];
    float* out      = (float*)d_out;
    float* out_zq   = out;                    // [N_ROWS*DIM]
    float* out_loss = out + OUT_ZQ_SIZE;      // [1]
    float* out_idx  = out + OUT_ZQ_SIZE + 1;  // [N_ROWS]

    float*  e2np    = (float*)d_ws;                          // 2048 floats
    float*  z2np    = (float*)((char*)d_ws + 8192);          // 32768 floats
    double* partial = (double*)((char*)d_ws + 8192 + 131072);// 256 doubles

    hipLaunchKernelGGL(sq_pairwise, dim3(128),  dim3(256), 0, stream, emb, e2np, K_EMB);
    hipLaunchKernelGGL(sq_pairwise, dim3(2048), dim3(256), 0, stream, z,   z2np, N_ROWS);
    hipLaunchKernelGGL(vq_main,     dim3(256),  dim3(256), 0, stream,
                       z, emb, e2np, z2np, out_zq, out_idx, partial);
    hipLaunchKernelGGL(finalize,    dim3(1),    dim3(1),   0, stream, partial, out_loss);
}

// Round 4
// 183.829 us; speedup vs baseline: 6.6488x; 3.0249x over previous
//
#include <hip/hip_runtime.h>

#define N_ROWS 32768
#define DIM    256
#define K_EMB  2048
#define OUT_ZQ_SIZE (N_ROWS * DIM)
#define DELTA  4e-4f
#define CAP    16

typedef short s16x8 __attribute__((ext_vector_type(8)));
typedef float f32x4 __attribute__((ext_vector_type(4)));

// min across each 16-lane DPP row via row_ror 8,4,2,1
__device__ inline float row16_min(float x) {
    int v = __builtin_amdgcn_update_dpp(0, __float_as_int(x), 0x128, 0xf, 0xf, false);
    x = fminf(x, __int_as_float(v));
    v = __builtin_amdgcn_update_dpp(0, __float_as_int(x), 0x124, 0xf, 0xf, false);
    x = fminf(x, __int_as_float(v));
    v = __builtin_amdgcn_update_dpp(0, __float_as_int(x), 0x122, 0xf, 0xf, false);
    x = fminf(x, __int_as_float(v));
    v = __builtin_amdgcn_update_dpp(0, __float_as_int(x), 0x121, 0xf, 0xf, false);
    x = fminf(x, __int_as_float(v));
    return x;
}

// ---------------- f32 -> bf16 (RNE) convert, 8 elems/thread ----------------
__global__ __launch_bounds__(256) void cvt_bf16(const float* __restrict__ src,
                                                unsigned short* __restrict__ dst,
                                                int n8) {
    int i = blockIdx.x * 256 + threadIdx.x;
    if (i >= n8) return;
    const float4* s = (const float4*)src + (size_t)i * 2;
    float4 v0 = s[0], v1 = s[1];
    float f[8] = {v0.x, v0.y, v0.z, v0.w, v1.x, v1.y, v1.z, v1.w};
    unsigned int r[8];
    #pragma unroll
    for (int j = 0; j < 8; j++) {
        unsigned int u = __float_as_uint(f[j]);
        r[j] = (u + 0x7fffu + ((u >> 16) & 1u)) >> 16;
    }
    uint4 o;
    o.x = r[0] | (r[1] << 16);
    o.y = r[2] | (r[3] << 16);
    o.z = r[4] | (r[5] << 16);
    o.w = r[6] | (r[7] << 16);
    *(uint4*)(dst + (size_t)i * 8) = o;
}

// ---------------- numpy-pairwise row sum of squares (exact) ----------------
__global__ __launch_bounds__(256) void sq_pairwise(const float* __restrict__ src,
                                                   float* __restrict__ dst,
                                                   int nrows) {
    int gid = blockIdx.x * 256 + threadIdx.x;
    int row = gid >> 4;
    int lane = gid & 15;
    if (row >= nrows) return;
    const float* p = src + row * DIM;
    int base = (lane >> 3) * 128 + (lane & 7);
    float r = __fmul_rn(p[base], p[base]);
    #pragma unroll
    for (int i = 1; i < 16; i++) {
        float v = p[base + 8 * i];
        r = __fadd_rn(r, __fmul_rn(v, v));
    }
    r = __fadd_rn(r, __shfl_xor(r, 1, 64));
    r = __fadd_rn(r, __shfl_xor(r, 2, 64));
    r = __fadd_rn(r, __shfl_xor(r, 4, 64));
    r = __fadd_rn(r, __shfl_xor(r, 8, 64));
    if (lane == 0) dst[row] = r;
}

// ---------------- MFMA screen + exact-rescore argmin ----------------
// grid 256 blocks x 256 thr (4 waves). Block: 128 rows. Wave w: rows w*32..+31.
__global__ __launch_bounds__(256) void vq_mfma(const float* __restrict__ z,
                                               const float* __restrict__ emb,
                                               const unsigned short* __restrict__ zb,
                                               const unsigned short* __restrict__ eb,
                                               const float* __restrict__ e2np,
                                               const float* __restrict__ z2np,
                                               float* __restrict__ out_idx) {
    __shared__ __attribute__((aligned(16))) unsigned short Bs[16384]; // 32KB: 128 cols x 128 k
    __shared__ float2 Cand[128][CAP];
    __shared__ int    Count[128];
    __shared__ float  RowMinS[128];

    const int t = threadIdx.x;
    const int l = t & 63;
    const int w = t >> 6;
    const int row0 = blockIdx.x * 128;

    if (t < 128) Count[t] = 0;

    // A fragments: full K=256 for rows w*32 + rt*16 + (l&15); k = kf*32 + (l>>4)*8
    s16x8 a[2][8];
    {
        const unsigned short* zbase = zb + (size_t)(row0 + w * 32) * DIM;
        #pragma unroll
        for (int rt = 0; rt < 2; rt++)
            #pragma unroll
            for (int kf = 0; kf < 8; kf++)
                a[rt][kf] = *(const s16x8*)(zbase + (rt * 16 + (l & 15)) * DIM + kf * 32 + (l >> 4) * 8);
    }

    const int colb = l & 15;
    const int swz  = (l & 7) << 4;      // XOR swizzle bits 4-6
    const int hi16 = (l >> 4) << 4;     // k-slice byte offset within frag row

    float m[8];
    #pragma unroll
    for (int i = 0; i < 8; i++) m[i] = 3.4e38f;

    __syncthreads();

    for (int kt = 0; kt < 16; kt++) {
        const int kcol0 = kt * 128;
        f32x4 acc[2][8];
        #pragma unroll
        for (int rt = 0; rt < 2; rt++)
            #pragma unroll
            for (int ct = 0; ct < 8; ct++)
                acc[rt][ct] = (f32x4){0.f, 0.f, 0.f, 0.f};

        float e2v[8];
        #pragma unroll
        for (int ct = 0; ct < 8; ct++) e2v[ct] = e2np[kcol0 + ct * 16 + colb];

        #pragma unroll
        for (int kh = 0; kh < 2; kh++) {
            __syncthreads();
            // stage 32KB (128 cols x 128 k bf16), source pre-swizzled so linear
            // LDS holds data[col][x ^ swz(col)]
            #pragma unroll
            for (int i = 0; i < 8; i++) {
                int s   = (w * 8 + i) * 64 + l;       // 16B slot 0..2047
                int col = s >> 4;
                int kk  = (s & 15) << 4;              // byte in 256B row
                const char* gsrc = (const char*)eb + (size_t)(kcol0 + col) * 512
                                   + kh * 256 + (kk ^ ((col & 7) << 4));
                char* ldst = (char*)Bs + (w * 8 + i) * 1024;
                __builtin_amdgcn_global_load_lds(
                    (const __attribute__((address_space(1))) unsigned int*)gsrc,
                    (__attribute__((address_space(3))) unsigned int*)ldst,
                    16, 0, 0);
            }
            __syncthreads();

            #pragma unroll
            for (int kf = 0; kf < 4; kf++) {
                const int koff = ((kf * 64) | hi16) ^ swz;
                const int ak = kh * 4 + kf;
                #pragma unroll
                for (int ct = 0; ct < 8; ct++) {
                    s16x8 b = *(const s16x8*)((const char*)Bs + (ct * 16 + colb) * 256 + koff);
                    acc[0][ct] = __builtin_amdgcn_mfma_f32_16x16x32_bf16(a[0][ak], b, acc[0][ct], 0, 0, 0);
                    acc[1][ct] = __builtin_amdgcn_mfma_f32_16x16x32_bf16(a[1][ak], b, acc[1][ct], 0, 0, 0);
                }
            }
        }

        // epilogue: s = e2 - 2*dot ; per-(lane,row) tile-min; running min; push window
        float tmin[8];
        #pragma unroll
        for (int rt = 0; rt < 2; rt++)
            #pragma unroll
            for (int reg = 0; reg < 4; reg++) {
                int r8 = rt * 4 + reg;
                float t0 = fmaf(-2.f, acc[rt][0][reg], e2v[0]);
                #pragma unroll
                for (int ct = 1; ct < 8; ct++)
                    t0 = fminf(t0, fmaf(-2.f, acc[rt][ct][reg], e2v[ct]));
                tmin[r8] = t0;
                m[r8] = fminf(m[r8], t0);
            }
        #pragma unroll
        for (int r8 = 0; r8 < 8; r8++) {
            float gm  = row16_min(m[r8]);
            float thr = gm + DELTA;
            if (tmin[r8] < thr) {
                int rt = r8 >> 2, reg = r8 & 3;
                int lrow = w * 32 + rt * 16 + (l >> 4) * 4 + reg;
                #pragma unroll
                for (int ct = 0; ct < 8; ct++) {
                    float s = fmaf(-2.f, acc[rt][ct][reg], e2v[ct]);
                    if (s < thr) {
                        int slot = atomicAdd(&Count[lrow], 1);
                        if (slot < CAP)
                            Cand[lrow][slot] = make_float2(s, __int_as_float(kcol0 + ct * 16 + colb));
                    }
                }
            }
        }
    }

    // final row minima
    #pragma unroll
    for (int r8 = 0; r8 < 8; r8++) {
        float gm = row16_min(m[r8]);
        if ((l & 15) == 0)
            RowMinS[w * 32 + (r8 >> 2) * 16 + (l >> 4) * 4 + (r8 & 3)] = gm;
    }
    __syncthreads();

    // cleanup: per row, resolve winner (exact fp32 chain identical to reference emulation)
    for (int rr = 0; rr < 32; rr++) {
        int lrow = w * 32 + rr;
        int grow = row0 + lrow;
        int c = Count[lrow];
        float thr = RowMinS[lrow] + DELTA;
        int widx;
        if (c > CAP) {
            // exhaustive exact (practically never taken)
            float bs = 3.4e38f; int bk = 0x7fffffff;
            float z2r = z2np[grow];
            const float* zr = z + (size_t)grow * DIM;
            for (int k0 = l; k0 < K_EMB; k0 += 64) {
                const float* er = emb + (size_t)k0 * DIM;
                float accd = 0.f;
                for (int d = 0; d < DIM; d++) accd = fmaf(zr[d], er[d], accd);
                float s = __fsub_rn(__fadd_rn(z2r, e2np[k0]), __fmul_rn(2.f, accd));
                if (s < bs || (s == bs && k0 < bk)) { bs = s; bk = k0; }
            }
            #pragma unroll
            for (int off = 32; off; off >>= 1) {
                float os = __shfl_xor(bs, off, 64);
                int   ok = __shfl_xor(bk, off, 64);
                if (os < bs || (os == bs && ok < bk)) { bs = os; bk = ok; }
            }
            widx = bk;
        } else {
            float cs = 3.4e38f; int ck = 0x7fffffff; bool eff = false;
            if (l < c) {
                float2 cd = Cand[lrow][l];
                if (cd.x < thr) { eff = true; ck = __float_as_int(cd.y); }
            }
            unsigned long long ball = __ballot(eff);
            int ne = __popcll(ball);
            if (ne == 1) {
                int src = __ffsll(ball) - 1;
                widx = __shfl(ck, src, 64);
            } else {
                if (eff) {
                    const float* zr = z + (size_t)grow * DIM;
                    const float* er = emb + (size_t)ck * DIM;
                    float accd = 0.f;
                    for (int d = 0; d < DIM; d++) accd = fmaf(zr[d], er[d], accd);
                    cs = __fsub_rn(__fadd_rn(z2np[grow], e2np[ck]), __fmul_rn(2.f, accd));
                }
                float bs = cs; int bk = ck;
                #pragma unroll
                for (int off = 32; off; off >>= 1) {
                    float os = __shfl_xor(bs, off, 64);
                    int   ok = __shfl_xor(bk, off, 64);
                    if (os < bs || (os == bs && ok < bk)) { bs = os; bk = ok; }
                }
                widx = bk;
            }
        }
        if (l == 0) out_idx[grow] = (float)widx;
    }
}

// ---------------- gather z_q + loss partials ----------------
__global__ __launch_bounds__(256) void vq_gather(const float* __restrict__ z,
                                                 const float* __restrict__ emb,
                                                 const float* __restrict__ out_idx,
                                                 float* __restrict__ out_zq,
                                                 double* __restrict__ partial) {
    __shared__ double Wsum[4];
    const int t = threadIdx.x;
    const int row0 = blockIdx.x * 128;
    double lsum;
    {
        int row = t >> 1;
        int d0  = (t & 1) * 128;
        int gi  = (int)out_idx[row0 + row];
        const float4* ev = (const float4*)(emb + (size_t)gi * DIM + d0);
        const float4* zv = (const float4*)(z + (size_t)(row0 + row) * DIM + d0);
        float4*       ov = (float4*)(out_zq + (size_t)(row0 + row) * DIM + d0);
        float fs = 0.f;
        #pragma unroll 8
        for (int q = 0; q < 32; q++) {
            float4 e = ev[q];
            float4 zz = zv[q];
            ov[q] = e;
            float dx = e.x - zz.x, dy = e.y - zz.y, dz = e.z - zz.z, dw = e.w - zz.w;
            fs += dx * dx + dy * dy + dz * dz + dw * dw;
        }
        lsum = (double)fs;
    }
    #pragma unroll
    for (int off = 32; off; off >>= 1) lsum += __shfl_down(lsum, off, 64);
    if ((t & 63) == 0) Wsum[t >> 6] = lsum;
    __syncthreads();
    if (t == 0) partial[blockIdx.x] = Wsum[0] + Wsum[1] + Wsum[2] + Wsum[3];
}

__global__ void finalize(const double* __restrict__ partial, float* __restrict__ out_loss) {
    double s = 0.0;
    for (int i = 0; i < 256; i++) s += partial[i];
    out_loss[0] = (float)(1.25 * s / (double)OUT_ZQ_SIZE);
}

extern "C" void kernel_launch(void* const* d_in, const int* in_sizes, int n_in,
                              void* d_out, int out_size, void* d_ws, size_t ws_size,
                              hipStream_t stream) {
    const float* z   = (const float*)d_in[0];
    const float* emb = (const float*)d_in[1];
    float* out      = (float*)d_out;
    float* out_zq   = out;
    float* out_loss = out + OUT_ZQ_SIZE;
    float* out_idx  = out + OUT_ZQ_SIZE + 1;

    float*  e2np    = (float*)d_ws;                            // 8KB
    float*  z2np    = (float*)((char*)d_ws + 8192);            // 128KB
    double* partial = (double*)((char*)d_ws + 8192 + 131072);  // 2KB

    // bf16 staging carved from out_zq region (fully rewritten by vq_gather later)
    unsigned short* eb = (unsigned short*)d_out;                        // 1MB
    unsigned short* zb = (unsigned short*)((char*)d_out + 1048576);     // 16MB

    hipLaunchKernelGGL(cvt_bf16,    dim3(256),  dim3(256), 0, stream, emb, eb, K_EMB * DIM / 8);
    hipLaunchKernelGGL(cvt_bf16,    dim3(4096), dim3(256), 0, stream, z,   zb, N_ROWS * DIM / 8);
    hipLaunchKernelGGL(sq_pairwise, dim3(128),  dim3(256), 0, stream, emb, e2np, K_EMB);
    hipLaunchKernelGGL(sq_pairwise, dim3(2048), dim3(256), 0, stream, z,   z2np, N_ROWS);
    hipLaunchKernelGGL(vq_mfma,     dim3(256),  dim3(256), 0, stream,
                       z, emb, zb, eb, e2np, z2np, out_idx);
    hipLaunchKernelGGL(vq_gather,   dim3(256),  dim3(256), 0, stream,
                       z, emb, out_idx, out_zq, partial);
    hipLaunchKernelGGL(finalize,    dim3(1),    dim3(1),   0, stream, partial, out_loss);
}

// Round 5
// 177.112 us; speedup vs baseline: 6.9009x; 1.0379x over previous
//
#include <hip/hip_runtime.h>

#define N_ROWS 32768
#define DIM    256
#define K_EMB  2048
#define OUT_ZQ_SIZE (N_ROWS * DIM)
#define DELTA  4e-4f
#define CAP    16

typedef short s16x8 __attribute__((ext_vector_type(8)));
typedef float f32x4 __attribute__((ext_vector_type(4)));

// min across each 16-lane DPP row via row_ror 8,4,2,1
__device__ inline float row16_min(float x) {
    int v = __builtin_amdgcn_update_dpp(0, __float_as_int(x), 0x128, 0xf, 0xf, false);
    x = fminf(x, __int_as_float(v));
    v = __builtin_amdgcn_update_dpp(0, __float_as_int(x), 0x124, 0xf, 0xf, false);
    x = fminf(x, __int_as_float(v));
    v = __builtin_amdgcn_update_dpp(0, __float_as_int(x), 0x122, 0xf, 0xf, false);
    x = fminf(x, __int_as_float(v));
    v = __builtin_amdgcn_update_dpp(0, __float_as_int(x), 0x121, 0xf, 0xf, false);
    x = fminf(x, __int_as_float(v));
    return x;
}

// ---------------- fused: f32 -> bf16 (RNE) + numpy-pairwise row sumsq ----------------
// block = 256 thr, covers 8 rows (2048 elems). cvt: 8 contiguous elems/thread.
// sq (threads 0-127): 16 lanes/row, exact numpy pairwise order (proven R2-R4).
__global__ __launch_bounds__(256) void prep(const float* __restrict__ src,
                                            unsigned short* __restrict__ dstb,
                                            float* __restrict__ dst2) {
    const int t = threadIdx.x;
    {
        size_t e0 = (size_t)blockIdx.x * 2048 + (size_t)t * 8;
        const float4* s = (const float4*)(src + e0);
        float4 v0 = s[0], v1 = s[1];
        float f[8] = {v0.x, v0.y, v0.z, v0.w, v1.x, v1.y, v1.z, v1.w};
        unsigned int r[8];
        #pragma unroll
        for (int j = 0; j < 8; j++) {
            unsigned int u = __float_as_uint(f[j]);
            r[j] = (u + 0x7fffu + ((u >> 16) & 1u)) >> 16;
        }
        uint4 o;
        o.x = r[0] | (r[1] << 16);
        o.y = r[2] | (r[3] << 16);
        o.z = r[4] | (r[5] << 16);
        o.w = r[6] | (r[7] << 16);
        *(uint4*)(dstb + e0) = o;
    }
    if (t < 128) {
        int row = blockIdx.x * 8 + (t >> 4);
        int lane = t & 15;
        const float* p = src + (size_t)row * DIM;
        int base = (lane >> 3) * 128 + (lane & 7);
        float r = __fmul_rn(p[base], p[base]);
        #pragma unroll
        for (int i = 1; i < 16; i++) {
            float v = p[base + 8 * i];
            r = __fadd_rn(r, __fmul_rn(v, v));
        }
        r = __fadd_rn(r, __shfl_xor(r, 1, 64));
        r = __fadd_rn(r, __shfl_xor(r, 2, 64));
        r = __fadd_rn(r, __shfl_xor(r, 4, 64));
        r = __fadd_rn(r, __shfl_xor(r, 8, 64));
        if (lane == 0) dst2[row] = r;
    }
}

// ---------------- MFMA screen + exact-rescore argmin (pipelined) ----------------
// grid 256 blocks x 256 thr (4 waves). Block: 128 rows. Wave w: rows w*32..+31.
// Double-buffered 64KB B tiles; T3-minimum 2-phase schedule:
//   STAGE(next); compute(cur); __syncthreads(); swap.
__global__ __launch_bounds__(256) void vq_mfma(const float* __restrict__ z,
                                               const float* __restrict__ emb,
                                               const unsigned short* __restrict__ zb,
                                               const unsigned short* __restrict__ eb,
                                               const float* __restrict__ e2np,
                                               const float* __restrict__ z2np,
                                               float* __restrict__ out_idx) {
    // 2 x 64KB: [buf][col(128)][d-bytes(512, swizzled low-7 by (col&7)<<4)]
    __shared__ __attribute__((aligned(16))) unsigned short Bs[2][32768];
    __shared__ float2 Cand[128][CAP];
    __shared__ int    Count[128];
    __shared__ float  RowMinS[128];

    const int t = threadIdx.x;
    const int l = t & 63;
    const int w = t >> 6;
    const int row0 = blockIdx.x * 128;

    if (t < 128) Count[t] = 0;

    // A fragments: full K=256 for rows w*32 + rt*16 + (l&15); d = kf*32 + (l>>4)*8
    s16x8 a[2][8];
    {
        const unsigned short* zbase = zb + (size_t)(row0 + w * 32) * DIM;
        #pragma unroll
        for (int rt = 0; rt < 2; rt++)
            #pragma unroll
            for (int kf = 0; kf < 8; kf++)
                a[rt][kf] = *(const s16x8*)(zbase + (rt * 16 + (l & 15)) * DIM + kf * 32 + (l >> 4) * 8);
    }

    const int colb = l & 15;
    const int swz  = (l & 7) << 4;      // XOR swizzle bits 4-6
    const int hi16 = (l >> 4) << 4;     // d-slice byte offset within 512B row

    // stage one full kt tile (128 cols x 256 d bf16 = 64KB) into Bs[buf]
    auto stage = [&](int buf, int ktile) {
        const size_t cbase = (size_t)(ktile * 128) * 512;
        char* lbase = (char*)&Bs[buf][0];
        #pragma unroll
        for (int i = 0; i < 16; i++) {
            int s   = (w * 16 + i) * 64 + l;      // 16B slot 0..4095
            int col = s >> 5;                     // 32 slots per col row
            int kk  = (s & 31) << 4;              // byte 0..511
            int ss  = (kk & ~127) | ((kk & 127) ^ ((col & 7) << 4));
            const char* gsrc = (const char*)eb + cbase + (size_t)col * 512 + ss;
            char* ldst = lbase + (w * 16 + i) * 1024;   // wave-uniform base (+ lane*16 by HW)
            __builtin_amdgcn_global_load_lds(
                (const __attribute__((address_space(1))) unsigned int*)gsrc,
                (__attribute__((address_space(3))) unsigned int*)ldst,
                16, 0, 0);
        }
    };

    float m[8];
    #pragma unroll
    for (int i = 0; i < 8; i++) m[i] = 3.4e38f;

    stage(0, 0);
    __syncthreads();   // buf0 ready; Count init visible

    int cur = 0;
    for (int kt = 0; kt < 16; kt++) {
        const int kcol0 = kt * 128;
        if (kt < 15) stage(cur ^ 1, kt + 1);   // async prefetch, in flight all phase

        float e2v[8];
        #pragma unroll
        for (int ct = 0; ct < 8; ct++) e2v[ct] = e2np[kcol0 + ct * 16 + colb];

        f32x4 acc[2][8];
        #pragma unroll
        for (int rt = 0; rt < 2; rt++)
            #pragma unroll
            for (int ct = 0; ct < 8; ct++)
                acc[rt][ct] = (f32x4){0.f, 0.f, 0.f, 0.f};

        const char* rbase = (const char*)&Bs[cur][0];
        #pragma unroll
        for (int kf = 0; kf < 8; kf++) {
            const int koff = (kf * 64 + hi16) ^ swz;
            #pragma unroll
            for (int ct = 0; ct < 8; ct++) {
                s16x8 b = *(const s16x8*)(rbase + (ct * 16 + colb) * 512 + koff);
                acc[0][ct] = __builtin_amdgcn_mfma_f32_16x16x32_bf16(a[0][kf], b, acc[0][ct], 0, 0, 0);
                acc[1][ct] = __builtin_amdgcn_mfma_f32_16x16x32_bf16(a[1][kf], b, acc[1][ct], 0, 0, 0);
            }
        }

        // epilogue: s = e2 - 2*dot ; per-(lane,row) tile-min; running min; push window
        float tmin[8];
        #pragma unroll
        for (int rt = 0; rt < 2; rt++)
            #pragma unroll
            for (int reg = 0; reg < 4; reg++) {
                int r8 = rt * 4 + reg;
                float t0 = fmaf(-2.f, acc[rt][0][reg], e2v[0]);
                #pragma unroll
                for (int ct = 1; ct < 8; ct++)
                    t0 = fminf(t0, fmaf(-2.f, acc[rt][ct][reg], e2v[ct]));
                tmin[r8] = t0;
                m[r8] = fminf(m[r8], t0);
            }
        #pragma unroll
        for (int r8 = 0; r8 < 8; r8++) {
            float gm  = row16_min(m[r8]);
            float thr = gm + DELTA;
            if (tmin[r8] < thr) {
                int rt = r8 >> 2, reg = r8 & 3;
                int lrow = w * 32 + rt * 16 + (l >> 4) * 4 + reg;
                #pragma unroll
                for (int ct = 0; ct < 8; ct++) {
                    float s = fmaf(-2.f, acc[rt][ct][reg], e2v[ct]);
                    if (s < thr) {
                        int slot = atomicAdd(&Count[lrow], 1);
                        if (slot < CAP)
                            Cand[lrow][slot] = make_float2(s, __int_as_float(kcol0 + ct * 16 + colb));
                    }
                }
            }
        }

        __syncthreads();   // drains stage loads (issued a full phase ago) + Cand writes
        cur ^= 1;
    }

    // final row minima
    #pragma unroll
    for (int r8 = 0; r8 < 8; r8++) {
        float gm = row16_min(m[r8]);
        if ((l & 15) == 0)
            RowMinS[w * 32 + (r8 >> 2) * 16 + (l >> 4) * 4 + (r8 & 3)] = gm;
    }
    __syncthreads();

    // cleanup: per row, resolve winner (exact fp32 chain identical to reference emulation)
    for (int rr = 0; rr < 32; rr++) {
        int lrow = w * 32 + rr;
        int grow = row0 + lrow;
        int c = Count[lrow];
        float thr = RowMinS[lrow] + DELTA;
        int widx;
        if (c > CAP) {
            // exhaustive exact (practically never taken)
            float bs = 3.4e38f; int bk = 0x7fffffff;
            float z2r = z2np[grow];
            const float* zr = z + (size_t)grow * DIM;
            for (int k0 = l; k0 < K_EMB; k0 += 64) {
                const float* er = emb + (size_t)k0 * DIM;
                float accd = 0.f;
                for (int d = 0; d < DIM; d++) accd = fmaf(zr[d], er[d], accd);
                float s = __fsub_rn(__fadd_rn(z2r, e2np[k0]), __fmul_rn(2.f, accd));
                if (s < bs || (s == bs && k0 < bk)) { bs = s; bk = k0; }
            }
            #pragma unroll
            for (int off = 32; off; off >>= 1) {
                float os = __shfl_xor(bs, off, 64);
                int   ok = __shfl_xor(bk, off, 64);
                if (os < bs || (os == bs && ok < bk)) { bs = os; bk = ok; }
            }
            widx = bk;
        } else {
            float cs = 3.4e38f; int ck = 0x7fffffff; bool eff = false;
            if (l < c) {
                float2 cd = Cand[lrow][l];
                if (cd.x < thr) { eff = true; ck = __float_as_int(cd.y); }
            }
            unsigned long long ball = __ballot(eff);
            int ne = __popcll(ball);
            if (ne == 1) {
                int src = __ffsll(ball) - 1;
                widx = __shfl(ck, src, 64);
            } else {
                if (eff) {
                    const float* zr = z + (size_t)grow * DIM;
                    const float* er = emb + (size_t)ck * DIM;
                    float accd = 0.f;
                    for (int d = 0; d < DIM; d++) accd = fmaf(zr[d], er[d], accd);
                    cs = __fsub_rn(__fadd_rn(z2np[grow], e2np[ck]), __fmul_rn(2.f, accd));
                }
                float bs = cs; int bk = ck;
                #pragma unroll
                for (int off = 32; off; off >>= 1) {
                    float os = __shfl_xor(bs, off, 64);
                    int   ok = __shfl_xor(bk, off, 64);
                    if (os < bs || (os == bs && ok < bk)) { bs = os; bk = ok; }
                }
                widx = bk;
            }
        }
        if (l == 0) out_idx[grow] = (float)widx;
    }
}

// ---------------- gather z_q + loss partials ----------------
__global__ __launch_bounds__(256) void vq_gather(const float* __restrict__ z,
                                                 const float* __restrict__ emb,
                                                 const float* __restrict__ out_idx,
                                                 float* __restrict__ out_zq,
                                                 double* __restrict__ partial) {
    __shared__ double Wsum[4];
    const int t = threadIdx.x;
    const int row0 = blockIdx.x * 128;
    double lsum;
    {
        int row = t >> 1;
        int d0  = (t & 1) * 128;
        int gi  = (int)out_idx[row0 + row];
        const float4* ev = (const float4*)(emb + (size_t)gi * DIM + d0);
        const float4* zv = (const float4*)(z + (size_t)(row0 + row) * DIM + d0);
        float4*       ov = (float4*)(out_zq + (size_t)(row0 + row) * DIM + d0);
        float fs = 0.f;
        #pragma unroll 8
        for (int q = 0; q < 32; q++) {
            float4 e = ev[q];
            float4 zz = zv[q];
            ov[q] = e;
            float dx = e.x - zz.x, dy = e.y - zz.y, dz = e.z - zz.z, dw = e.w - zz.w;
            fs += dx * dx + dy * dy + dz * dz + dw * dw;
        }
        lsum = (double)fs;
    }
    #pragma unroll
    for (int off = 32; off; off >>= 1) lsum += __shfl_down(lsum, off, 64);
    if ((t & 63) == 0) Wsum[t >> 6] = lsum;
    __syncthreads();
    if (t == 0) partial[blockIdx.x] = Wsum[0] + Wsum[1] + Wsum[2] + Wsum[3];
}

__global__ void finalize(const double* __restrict__ partial, float* __restrict__ out_loss) {
    double s = 0.0;
    for (int i = 0; i < 256; i++) s += partial[i];
    out_loss[0] = (float)(1.25 * s / (double)OUT_ZQ_SIZE);
}

extern "C" void kernel_launch(void* const* d_in, const int* in_sizes, int n_in,
                              void* d_out, int out_size, void* d_ws, size_t ws_size,
                              hipStream_t stream) {
    const float* z   = (const float*)d_in[0];
    const float* emb = (const float*)d_in[1];
    float* out      = (float*)d_out;
    float* out_zq   = out;
    float* out_loss = out + OUT_ZQ_SIZE;
    float* out_idx  = out + OUT_ZQ_SIZE + 1;

    float*  e2np    = (float*)d_ws;                            // 8KB
    float*  z2np    = (float*)((char*)d_ws + 8192);            // 128KB
    double* partial = (double*)((char*)d_ws + 8192 + 131072);  // 2KB

    // bf16 staging carved from out_zq region (fully rewritten by vq_gather later;
    // vq_mfma reads eb everywhere but only its OWN rows of zb, and the grid
    // boundary before vq_gather orders all eb reads before the overwrite)
    unsigned short* eb = (unsigned short*)d_out;                        // 1MB
    unsigned short* zb = (unsigned short*)((char*)d_out + 1048576);     // 16MB

    hipLaunchKernelGGL(prep,      dim3(256),  dim3(256), 0, stream, emb, eb, e2np);
    hipLaunchKernelGGL(prep,      dim3(4096), dim3(256), 0, stream, z,   zb, z2np);
    hipLaunchKernelGGL(vq_mfma,   dim3(256),  dim3(256), 0, stream,
                       z, emb, zb, eb, e2np, z2np, out_idx);
    hipLaunchKernelGGL(vq_gather, dim3(256),  dim3(256), 0, stream,
                       z, emb, out_idx, out_zq, partial);
    hipLaunchKernelGGL(finalize,  dim3(1),    dim3(1),   0, stream, partial, out_loss);
}